// Round 3
// baseline (1487.505 us; speedup 1.0000x reference)
//
#include <hip/hip_runtime.h>

#define T_TOK 4096
#define DM 1024
#define NH 16
#define HDIM 64
#define DFF_ 2048
#define NE 8

typedef __bf16 bf16;
typedef __bf16 bf16x8 __attribute__((ext_vector_type(8)));
typedef __bf16 bf16x4 __attribute__((ext_vector_type(4)));
typedef float f32x4 __attribute__((ext_vector_type(4)));

__device__ __forceinline__ void gload_lds16(const bf16* g, bf16* l) {
  __builtin_amdgcn_global_load_lds(
      (const __attribute__((address_space(1))) void*)g,
      (__attribute__((address_space(3))) void*)l, 16, 0, 0);
}

// ---------------- rmsnorm; MODE 0: single bf16 plane, MODE 1: hi/lo split ----------------
template <int SPLIT>
__global__ __launch_bounds__(256) void rmsnorm_k(
    const float* __restrict__ x, const float* __restrict__ w,
    bf16* __restrict__ outh, bf16* __restrict__ outl) {
  const int t = blockIdx.x, tid = threadIdx.x;
  __shared__ float red[4];
  const f32x4 xv = *(const f32x4*)(x + (size_t)t * DM + tid * 4);
  float ss = xv.x * xv.x + xv.y * xv.y + xv.z * xv.z + xv.w * xv.w;
#pragma unroll
  for (int o = 32; o; o >>= 1) ss += __shfl_xor(ss, o);
  if ((tid & 63) == 0) red[tid >> 6] = ss;
  __syncthreads();
  const float rs = rsqrtf((red[0] + red[1] + red[2] + red[3]) * (1.f / DM) + 1e-6f);
  const f32x4 wv = *(const f32x4*)(w + tid * 4);
  float vv[4] = {xv.x * rs * wv.x, xv.y * rs * wv.y, xv.z * rs * wv.z, xv.w * rs * wv.w};
  bf16x4 h, l;
#pragma unroll
  for (int i = 0; i < 4; i++) {
    h[i] = (bf16)vv[i];
    l[i] = (bf16)(vv[i] - (float)h[i]);
  }
  *(bf16x4*)(outh + (size_t)t * DM + tid * 4) = h;
  if constexpr (SPLIT) *(bf16x4*)(outl + (size_t)t * DM + tid * 4) = l;
}

// ---------------- transpose fp32[R][C] -> bf16[C][R]; optional lo plane ----------------
template <int SPLIT>
__global__ __launch_bounds__(256) void transpose_k(
    const float* __restrict__ src, bf16* __restrict__ dsth, bf16* __restrict__ dstl,
    int R, int C, long sstride, long dstride) {
  src += (long)blockIdx.z * sstride;
  dsth += (long)blockIdx.z * dstride;
  __shared__ float tle[32][33];
  const int tx = threadIdx.x, ty = threadIdx.y;
  const int c0 = blockIdx.x * 32, r0 = blockIdx.y * 32;
#pragma unroll
  for (int j = 0; j < 4; j++)
    tle[ty + 8 * j][tx] = src[(size_t)(r0 + ty + 8 * j) * C + c0 + tx];
  __syncthreads();
#pragma unroll
  for (int j = 0; j < 4; j++) {
    const float v = tle[tx][ty + 8 * j];
    const bf16 h = (bf16)v;
    dsth[(size_t)(c0 + ty + 8 * j) * R + r0 + tx] = h;
    if constexpr (SPLIT) {
      dstl[(size_t)(c0 + ty + 8 * j) * R + r0 + tx] = (bf16)(v - (float)h);
    }
  }
}

// ---------------- split-bf16 fp32-accurate GEMM (Ootomo 3-term), BT stored [N][K] ----------
// MODE 0: rkv out fp32, pad-mask cols>=1024.  MODE 1: out fp32 + residual extraF.
template <int K, int N, int MODE>
__global__ __launch_bounds__(256) void gemm_split_k(
    const bf16* __restrict__ Ah, const bf16* __restrict__ Al,
    const bf16* __restrict__ Bh, const bf16* __restrict__ Bl,
    float* __restrict__ Cout, const float* __restrict__ extraF,
    const int* __restrict__ pad) {
  __shared__ bf16 Ash[128 * 32], Asl[128 * 32], Bsh[128 * 32], Bsl[128 * 32];
  const int tid = threadIdx.x, w = tid >> 6, lane = tid & 63;
  const int n0 = blockIdx.x * 128, m0 = blockIdx.y * 128;
  const int sr0 = (w * 2 + 0) * 16 + (lane >> 2);
  const int sr1 = (w * 2 + 1) * 16 + (lane >> 2);
  const int sc = (lane & 3) * 8;
  const size_t ao0 = (size_t)(m0 + sr0) * K + sc, ao1 = (size_t)(m0 + sr1) * K + sc;
  const size_t bo0 = (size_t)(n0 + sr0) * K + sc, bo1 = (size_t)(n0 + sr1) * K + sc;

  f32x4 acc[4][4] = {};
  const int wm = w >> 1, wn = w & 1;
  const int fm = (wm * 64 + (lane & 15)) * 32 + (lane >> 4) * 8;
  const int fn = (wn * 64 + (lane & 15)) * 32 + (lane >> 4) * 8;
  const int l0 = (w * 2 + 0) * 512, l1 = (w * 2 + 1) * 512;

  for (int kt = 0; kt < K; kt += 32) {
    gload_lds16(Ah + ao0 + kt, Ash + l0);
    gload_lds16(Ah + ao1 + kt, Ash + l1);
    gload_lds16(Al + ao0 + kt, Asl + l0);
    gload_lds16(Al + ao1 + kt, Asl + l1);
    gload_lds16(Bh + bo0 + kt, Bsh + l0);
    gload_lds16(Bh + bo1 + kt, Bsh + l1);
    gload_lds16(Bl + bo0 + kt, Bsl + l0);
    gload_lds16(Bl + bo1 + kt, Bsl + l1);
    __syncthreads();
    bf16x8 afh[4], afl[4], bfh[4], bfl[4];
#pragma unroll
    for (int i = 0; i < 4; i++) {
      afh[i] = *(const bf16x8*)(Ash + fm + i * 512);
      afl[i] = *(const bf16x8*)(Asl + fm + i * 512);
      bfh[i] = *(const bf16x8*)(Bsh + fn + i * 512);
      bfl[i] = *(const bf16x8*)(Bsl + fn + i * 512);
    }
#pragma unroll
    for (int mi = 0; mi < 4; mi++)
#pragma unroll
      for (int ni = 0; ni < 4; ni++) {
        acc[mi][ni] = __builtin_amdgcn_mfma_f32_16x16x32_bf16(afh[mi], bfh[ni], acc[mi][ni], 0, 0, 0);
        acc[mi][ni] = __builtin_amdgcn_mfma_f32_16x16x32_bf16(afh[mi], bfl[ni], acc[mi][ni], 0, 0, 0);
        acc[mi][ni] = __builtin_amdgcn_mfma_f32_16x16x32_bf16(afl[mi], bfh[ni], acc[mi][ni], 0, 0, 0);
      }
    __syncthreads();
  }

  const int qr = (lane >> 4) * 4, cl = lane & 15;
#pragma unroll
  for (int mi = 0; mi < 4; mi++) {
#pragma unroll
    for (int r = 0; r < 4; r++) {
      const int row = m0 + wm * 64 + mi * 16 + qr + r;
      if constexpr (MODE == 0) {
        const float mf = (pad[row] != 0) ? 1.f : 0.f;
#pragma unroll
        for (int ni = 0; ni < 4; ni++) {
          const int col = n0 + wn * 64 + ni * 16 + cl;
          float v = acc[mi][ni][r];
          if (col >= DM) v *= mf;
          Cout[(size_t)row * N + col] = v;
        }
      } else {
#pragma unroll
        for (int ni = 0; ni < 4; ni++) {
          const int col = n0 + wn * 64 + ni * 16 + cl;
          Cout[(size_t)row * N + col] = acc[mi][ni][r] + extraF[(size_t)row * N + col];
        }
      }
    }
  }
}

// ---------------- plain bf16 GEMM for MoE (post-routing, error-tolerant) ----------------
// MODE 2: moe1 (gathered A rows via ptoken, silu, bf16 out). MODE 3: moe2 (*gate, fp32 out).
template <int K, int MODE, int N>
__global__ __launch_bounds__(256) void gemm_k(
    const bf16* __restrict__ A, const bf16* __restrict__ BT, void* __restrict__ Cout,
    const float* __restrict__ extraF, const int* __restrict__ offsets,
    const int* __restrict__ counts, const int* __restrict__ ptoken) {
  __shared__ bf16 As[128 * 32];
  __shared__ bf16 Bs[128 * 32];
  const int tid = threadIdx.x, w = tid >> 6, lane = tid & 63;
  const int n0 = blockIdx.x * 128, m0 = blockIdx.y * 128;
  const int e = blockIdx.z;
  const int cnt = counts[e], offs = offsets[e];
  if (m0 >= cnt) return;
  const int sr0 = (w * 2 + 0) * 16 + (lane >> 2);
  const int sr1 = (w * 2 + 1) * 16 + (lane >> 2);
  const int sc = (lane & 3) * 8;
  const bf16 *a0, *a1;
  if constexpr (MODE == 2) {
    const int g0 = (m0 + sr0 < cnt) ? ptoken[offs + m0 + sr0] : 0;
    const int g1 = (m0 + sr1 < cnt) ? ptoken[offs + m0 + sr1] : 0;
    a0 = A + (size_t)g0 * K + sc;
    a1 = A + (size_t)g1 * K + sc;
  } else {
    const int g0 = offs + ((m0 + sr0 < cnt) ? m0 + sr0 : cnt - 1);
    const int g1 = offs + ((m0 + sr1 < cnt) ? m0 + sr1 : cnt - 1);
    a0 = A + (size_t)g0 * K + sc;
    a1 = A + (size_t)g1 * K + sc;
  }
  const bf16* btb = BT + (size_t)e * N * K;
  const bf16* b0 = btb + (size_t)(n0 + sr0) * K + sc;
  const bf16* b1 = btb + (size_t)(n0 + sr1) * K + sc;

  f32x4 acc[4][4] = {};
  const int wm = w >> 1, wn = w & 1;
  const int fm = (wm * 64 + (lane & 15)) * 32 + (lane >> 4) * 8;
  const int fn = (wn * 64 + (lane & 15)) * 32 + (lane >> 4) * 8;
  const int l0 = (w * 2 + 0) * 512, l1 = (w * 2 + 1) * 512;

  for (int kt = 0; kt < K; kt += 32) {
    gload_lds16(a0 + kt, As + l0);
    gload_lds16(a1 + kt, As + l1);
    gload_lds16(b0 + kt, Bs + l0);
    gload_lds16(b1 + kt, Bs + l1);
    __syncthreads();
    bf16x8 af[4], bfv[4];
#pragma unroll
    for (int i = 0; i < 4; i++) af[i] = *(const bf16x8*)(As + fm + i * 512);
#pragma unroll
    for (int i = 0; i < 4; i++) bfv[i] = *(const bf16x8*)(Bs + fn + i * 512);
#pragma unroll
    for (int mi = 0; mi < 4; mi++)
#pragma unroll
      for (int ni = 0; ni < 4; ni++)
        acc[mi][ni] =
            __builtin_amdgcn_mfma_f32_16x16x32_bf16(af[mi], bfv[ni], acc[mi][ni], 0, 0, 0);
    __syncthreads();
  }

  const int qr = (lane >> 4) * 4, cl = lane & 15;
#pragma unroll
  for (int mi = 0; mi < 4; mi++) {
#pragma unroll
    for (int r = 0; r < 4; r++) {
      const int row = m0 + wm * 64 + mi * 16 + qr + r;
      if (row >= cnt) continue;
      const size_t p = (size_t)(offs + row);
      if constexpr (MODE == 2) {
#pragma unroll
        for (int ni = 0; ni < 4; ni++) {
          const int col = n0 + wn * 64 + ni * 16 + cl;
          const float v = acc[mi][ni][r];
          ((bf16*)Cout)[p * N + col] = (bf16)(v / (1.f + __expf(-v)));  // silu
        }
      } else {
        const float g = extraF[p];
#pragma unroll
        for (int ni = 0; ni < 4; ni++) {
          const int col = n0 + wn * 64 + ni * 16 + cl;
          ((float*)Cout)[p * N + col] = acc[mi][ni][r] * g;
        }
      }
    }
  }
}

// ---------------- bidirectional RWKV scan; fp32 atomic accumulate into y ----------------
__global__ __launch_bounds__(256) void scan_k(
    const float* __restrict__ rkv, const float* __restrict__ decay,
    float* __restrict__ yacc) {
  const int wg = blockIdx.x;
  const int dir = wg & 1, kg = (wg >> 1) & 3, h = (wg >> 3) & 15, b = wg >> 7;
  const int tid = threadIdx.x, w = tid >> 6, lane = tid & 63;
  const int kb = kg * 16 + w * 4;
  __shared__ float ylds[4][16][64];

  const f32x4 dc = *(const f32x4*)(decay + h * HDIM + kb);
  const float wd0 = expf(-expf(dc.x)), wd1 = expf(-expf(dc.y));
  const float wd2 = expf(-expf(dc.z)), wd3 = expf(-expf(dc.w));

  const long base = (long)b * 2048 * 3072;
  const long start = dir ? (long)2047 * 3072 : 0;
  const long stp = dir ? -3072 : 3072;
  const float* rp = rkv + base + start + h * HDIM + kb;
  const float* kp = rp + 1024;
  const float* vp = rkv + base + start + 2048 + h * HDIM + lane;

  float S0 = 0.f, S1 = 0.f, S2 = 0.f, S3 = 0.f;
  f32x4 ka[8], ra[8], kc[8], rc[8];
  float va[8], vc[8], yb[16];
#pragma unroll
  for (int s = 0; s < 8; s++) {
    ka[s] = *(const f32x4*)(kp + (long)s * stp);
    ra[s] = *(const f32x4*)(rp + (long)s * stp);
    va[s] = vp[(long)s * stp];
  }
  for (int c = 0; c < 128; ++c) {
#pragma unroll
    for (int s = 0; s < 8; s++) {
      kc[s] = *(const f32x4*)(kp + (long)(8 + s) * stp);
      rc[s] = *(const f32x4*)(rp + (long)(8 + s) * stp);
      vc[s] = vp[(long)(8 + s) * stp];
    }
#pragma unroll
    for (int s = 0; s < 8; s++) {
      const float vv = va[s];
      const f32x4 Kv = ka[s], Rv = ra[s];
      yb[s] = Rv.x * S0 + Rv.y * S1 + Rv.z * S2 + Rv.w * S3;
      S0 = wd0 * S0 + Kv.x * vv;
      S1 = wd1 * S1 + Kv.y * vv;
      S2 = wd2 * S2 + Kv.z * vv;
      S3 = wd3 * S3 + Kv.w * vv;
    }
    if (c < 127) {
#pragma unroll
      for (int s = 0; s < 8; s++) {
        ka[s] = *(const f32x4*)(kp + (long)(16 + s) * stp);
        ra[s] = *(const f32x4*)(rp + (long)(16 + s) * stp);
        va[s] = vp[(long)(16 + s) * stp];
      }
    }
#pragma unroll
    for (int s = 0; s < 8; s++) {
      const float vv = vc[s];
      const f32x4 Kv = kc[s], Rv = rc[s];
      yb[8 + s] = Rv.x * S0 + Rv.y * S1 + Rv.z * S2 + Rv.w * S3;
      S0 = wd0 * S0 + Kv.x * vv;
      S1 = wd1 * S1 + Kv.y * vv;
      S2 = wd2 * S2 + Kv.z * vv;
      S3 = wd3 * S3 + Kv.w * vv;
    }
    kp += 16 * stp;
    rp += 16 * stp;
    vp += 16 * stp;
#pragma unroll
    for (int s = 0; s < 16; s++) ylds[w][s][lane] = yb[s];
    __syncthreads();
    {
      const int idx = tid * 4, tl = idx >> 6, v0 = idx & 63;
      const f32x4 s0 = *(const f32x4*)&ylds[0][tl][v0];
      const f32x4 s1 = *(const f32x4*)&ylds[1][tl][v0];
      const f32x4 s2 = *(const f32x4*)&ylds[2][tl][v0];
      const f32x4 s3 = *(const f32x4*)&ylds[3][tl][v0];
      const f32x4 sm = s0 + s1 + s2 + s3;
      const int sg = dir ? (2047 - (c * 16 + tl)) : (c * 16 + tl);
      float* yp = yacc + (size_t)(b * 2048 + sg) * DM + h * HDIM + v0;
      atomicAdd(yp + 0, sm.x);
      atomicAdd(yp + 1, sm.y);
      atomicAdd(yp + 2, sm.z);
      atomicAdd(yp + 3, sm.w);
    }
    __syncthreads();
  }
}

// ---------------- y = yacc + 2*c_t*v  ->  hi/lo bf16 planes ----------------
__global__ __launch_bounds__(256) void sum_k(
    const float* __restrict__ rkv, const float* __restrict__ bonus,
    const float* __restrict__ yacc, bf16* __restrict__ yh, bf16* __restrict__ yl) {
  const int tok = blockIdx.x, tid = threadIdx.x;
  const int hv = tid * 4;
  const float* bse = rkv + (size_t)tok * 3072;
  const f32x4 r4 = *(const f32x4*)(bse + hv);
  const f32x4 k4 = *(const f32x4*)(bse + 1024 + hv);
  const f32x4 v4 = *(const f32x4*)(bse + 2048 + hv);
  const f32x4 u4 = *(const f32x4*)(bonus + hv);
  float p = r4.x * u4.x * k4.x + r4.y * u4.y * k4.y + r4.z * u4.z * k4.z + r4.w * u4.w * k4.w;
  p += __shfl_xor(p, 1);
  p += __shfl_xor(p, 2);
  p += __shfl_xor(p, 4);
  p += __shfl_xor(p, 8);  // reduce over the 16 lanes of this head
  const float c2 = 2.f * p;  // bonus appears once per direction
  const f32x4 ya = *(const f32x4*)(yacc + (size_t)tok * DM + hv);
  float yv[4] = {ya.x + c2 * v4.x, ya.y + c2 * v4.y, ya.z + c2 * v4.z, ya.w + c2 * v4.w};
  bf16x4 h, l;
#pragma unroll
  for (int i = 0; i < 4; i++) {
    h[i] = (bf16)yv[i];
    l[i] = (bf16)(yv[i] - (float)h[i]);
  }
  *(bf16x4*)(yh + (size_t)tok * DM + hv) = h;
  *(bf16x4*)(yl + (size_t)tok * DM + hv) = l;
}

// ---------------- router: fp32 rmsnorm+logits+softmax+top2 per token ----------------
__global__ __launch_bounds__(256) void router_k(
    const float* __restrict__ x2, const float* __restrict__ nw, const float* __restrict__ rw,
    float* __restrict__ gates, int* __restrict__ topi, int* __restrict__ counts,
    float* __restrict__ psum) {
  const int t = blockIdx.x, tid = threadIdx.x, lane = tid & 63, wv = tid >> 6;
  __shared__ float red[4];
  __shared__ float lacc[4][8];
  const f32x4 xv = *(const f32x4*)(x2 + (size_t)t * DM + tid * 4);
  float ss = xv.x * xv.x + xv.y * xv.y + xv.z * xv.z + xv.w * xv.w;
#pragma unroll
  for (int o = 32; o; o >>= 1) ss += __shfl_xor(ss, o);
  if (!lane) red[wv] = ss;
  __syncthreads();
  const float rs = rsqrtf((red[0] + red[1] + red[2] + red[3]) * (1.f / DM) + 1e-6f);
  const f32x4 wv4 = *(const f32x4*)(nw + tid * 4);
  float a[8] = {0, 0, 0, 0, 0, 0, 0, 0};
  const float xns[4] = {xv.x * rs * wv4.x, xv.y * rs * wv4.y, xv.z * rs * wv4.z,
                        xv.w * rs * wv4.w};
#pragma unroll
  for (int j = 0; j < 4; j++) {
    const float* rwp = rw + (size_t)(tid * 4 + j) * NE;
    const f32x4 q0 = *(const f32x4*)rwp;
    const f32x4 q1 = *(const f32x4*)(rwp + 4);
    a[0] += xns[j] * q0.x; a[1] += xns[j] * q0.y; a[2] += xns[j] * q0.z; a[3] += xns[j] * q0.w;
    a[4] += xns[j] * q1.x; a[5] += xns[j] * q1.y; a[6] += xns[j] * q1.z; a[7] += xns[j] * q1.w;
  }
#pragma unroll
  for (int e2 = 0; e2 < 8; e2++) {
    float v = a[e2];
#pragma unroll
    for (int o = 32; o; o >>= 1) v += __shfl_xor(v, o);
    a[e2] = v;
  }
  if (!lane) {
#pragma unroll
    for (int e2 = 0; e2 < 8; e2++) lacc[wv][e2] = a[e2];
  }
  __syncthreads();
  if (tid == 0) {
    float l[8];
    for (int e2 = 0; e2 < 8; e2++)
      l[e2] = lacc[0][e2] + lacc[1][e2] + lacc[2][e2] + lacc[3][e2];
    float mx = l[0];
    for (int e2 = 1; e2 < 8; e2++) mx = fmaxf(mx, l[e2]);
    float pr[8], s = 0.f;
    for (int e2 = 0; e2 < 8; e2++) { pr[e2] = expf(l[e2] - mx); s += pr[e2]; }
    const float inv = 1.f / s;
    for (int e2 = 0; e2 < 8; e2++) pr[e2] *= inv;
    int i1 = 0; float v1 = pr[0];
    for (int e2 = 1; e2 < 8; e2++) if (pr[e2] > v1) { v1 = pr[e2]; i1 = e2; }
    int i2 = -1; float v2 = -1.f;
    for (int e2 = 0; e2 < 8; e2++) if (e2 != i1 && pr[e2] > v2) { v2 = pr[e2]; i2 = e2; }
    const float dn = 1.f / (v1 + v2);
    gates[t * 2] = v1 * dn;
    gates[t * 2 + 1] = v2 * dn;
    topi[t * 2] = i1;
    topi[t * 2 + 1] = i2;
    atomicAdd(&counts[i1], 1);
    atomicAdd(&counts[i2], 1);
    for (int e2 = 0; e2 < 8; e2++) atomicAdd(&psum[e2], pr[e2]);
  }
}

// ---------------- routing scan + aux ----------------
__global__ void r2_k(const int* __restrict__ counts, const float* __restrict__ psum,
                     int* __restrict__ offsets, int* __restrict__ cursor,
                     float* __restrict__ auxout) {
  if (threadIdx.x == 0 && blockIdx.x == 0) {
    int o = 0;
    float a = 0.f;
    for (int e = 0; e < 8; e++) {
      offsets[e] = o;
      cursor[e] = o;
      o += counts[e];
      a += (float)counts[e] * psum[e];
    }
    auxout[0] = a * (8.f / (8192.f * 4096.f));
  }
}

__global__ __launch_bounds__(256) void r3_k(
    const int* __restrict__ topi, const float* __restrict__ gates, int* __restrict__ cursor,
    int* __restrict__ ptoken, float* __restrict__ pgate, int* __restrict__ ppos) {
  const int i = blockIdx.x * 256 + threadIdx.x;
  if (i >= 8192) return;
  const int e = topi[i];
  const int pos = atomicAdd(&cursor[e], 1);
  ptoken[pos] = i >> 1;
  pgate[pos] = gates[i];
  ppos[i] = pos;
}

// ---------------- final: out = x2 + pair0 + pair1 ----------------
__global__ __launch_bounds__(256) void final_k(
    const float* __restrict__ x2, const float* __restrict__ pout,
    const int* __restrict__ ppos, float* __restrict__ out) {
  const int idx = blockIdx.x * 256 + threadIdx.x;
  const int t = idx >> 8, c = (idx & 255) * 4;
  const int p0 = ppos[t * 2], p1 = ppos[t * 2 + 1];
  const f32x4 a = *(const f32x4*)(x2 + (size_t)t * DM + c);
  const f32x4 b0 = *(const f32x4*)(pout + (size_t)p0 * DM + c);
  const f32x4 b1 = *(const f32x4*)(pout + (size_t)p1 * DM + c);
  const f32x4 o = a + b0 + b1;
  *(f32x4*)(out + (size_t)t * DM + c) = o;
}

extern "C" void kernel_launch(void* const* d_in, const int* in_sizes, int n_in,
                              void* d_out, int out_size, void* d_ws, size_t ws_size,
                              hipStream_t stream) {
  (void)in_sizes; (void)n_in; (void)out_size; (void)ws_size;
  const float* x = (const float*)d_in[0];
  const int* pad = (const int*)d_in[1];
  const float* n1w = (const float*)d_in[2];
  const float* n2w = (const float*)d_in[3];
  const float* Wr = (const float*)d_in[4];
  const float* Wk = (const float*)d_in[5];
  const float* Wv = (const float*)d_in[6];
  const float* Wo = (const float*)d_in[7];
  const float* decay = (const float*)d_in[8];
  const float* bonus = (const float*)d_in[9];
  const float* rw = (const float*)d_in[10];
  const float* w1 = (const float*)d_in[11];
  const float* w2 = (const float*)d_in[12];
  float* out = (float*)d_out;
  char* ws = (char*)d_ws;

  // workspace layout (lifetime-aliased), peak ~180.6 MB (within proven footprint)
  float* rkv = (float*)(ws + 0);                 // [4096][3072] fp32, 50.3MB
  float* yacc = (float*)(ws + 50331648);         // [4096][1024] fp32, 16.8MB
  float* x2 = (float*)(ws + 67108864);           // 16.8MB
  bf16* xh = (bf16*)(ws + 83886080);             // hi plane 8.4MB (xn1 -> y -> xn2)
  bf16* xl = (bf16*)(ws + 92274688);             // lo plane 8.4MB
  bf16* wbh = (bf16*)(ws + 100663296);           // Wrkv^T hi [3072][1024], 6.3MB
  bf16* wbl = (bf16*)(ws + 106954752);           // Wrkv^T lo, 6.3MB -> ends 113246208
  float* pout = (float*)(ws + 113246208);        // [8192][1024] fp32, 33.6MB -> 146800640
  bf16* hbuf = (bf16*)(ws + 146800640);          // [8192][2048] bf16, 33.6MB -> 180355072
  char* sm = ws + 180355072;                     // tables ~164KB
  int* counts = (int*)(sm);
  float* psum = (float*)(sm + 32);
  int* offsets = (int*)(sm + 64);
  int* cursor = (int*)(sm + 96);
  int* topi = (int*)(sm + 128);
  float* gates = (float*)(sm + 32896);
  int* ppos = (int*)(sm + 65664);
  int* ptoken = (int*)(sm + 98432);
  float* pgate = (float*)(sm + 131712);
  // aliased after scan/sum (rkv, yacc dead):
  bf16* w1t = (bf16*)(ws + 0);                   // [8][2048][1024] bf16, 33.6MB
  bf16* w2t = (bf16*)(ws + 33554432);            // [8][1024][2048] bf16, 33.6MB -> 67108864
  // Wo hi/lo aliases Wrkv planes (dead after QKV GEMM):
  bf16* woh = wbh;
  bf16* wol = (bf16*)(ws + 102760448);           // 100663296 + 1024*1024*2

  const dim3 tb(32, 8);

  // 1) xn1 = rmsnorm(x) -> hi/lo
  rmsnorm_k<1><<<4096, 256, 0, stream>>>(x, n1w, xh, xl);
  // 2) Wrkv^T hi/lo
  transpose_k<1><<<dim3(32, 32, 1), tb, 0, stream>>>(Wr, wbh, wbl, 1024, 1024, 0, 0);
  transpose_k<1><<<dim3(32, 32, 1), tb, 0, stream>>>(Wk, wbh + 1048576, wbl + 1048576, 1024, 1024, 0, 0);
  transpose_k<1><<<dim3(32, 32, 1), tb, 0, stream>>>(Wv, wbh + 2097152, wbl + 2097152, 1024, 1024, 0, 0);
  // 3) rkv = xn1 @ [Wr|Wk|Wv] (split fp32-accurate), pad-mask k,v planes
  gemm_split_k<1024, 3072, 0><<<dim3(24, 32, 1), 256, 0, stream>>>(
      xh, xl, wbh, wbl, rkv, nullptr, pad);
  // 4) y accumulation (scan, fp32 atomics)
  hipMemsetAsync(yacc, 0, 16777216, stream);
  scan_k<<<256, 256, 0, stream>>>(rkv, decay, yacc);
  // 5) Wo^T hi/lo
  transpose_k<1><<<dim3(32, 32, 1), tb, 0, stream>>>(Wo, woh, wol, 1024, 1024, 0, 0);
  // 6) y = yacc + 2*ct*v -> hi/lo planes (reuse xh/xl)
  sum_k<<<4096, 256, 0, stream>>>(rkv, bonus, yacc, xh, xl);
  // 7) x2 = x + y @ Wo (split fp32-accurate)
  gemm_split_k<1024, 1024, 1><<<dim3(8, 32, 1), 256, 0, stream>>>(
      xh, xl, woh, wol, x2, x, nullptr);
  // 8) xn2 = rmsnorm(x2) single bf16 (for MoE)
  rmsnorm_k<0><<<4096, 256, 0, stream>>>(x2, n2w, xh, nullptr);
  // 9) routing (fp32 logits from fp32 x2)
  hipMemsetAsync(sm, 0, 64, stream);
  router_k<<<4096, 256, 0, stream>>>(x2, n2w, rw, gates, topi, counts, psum);
  r2_k<<<1, 64, 0, stream>>>(counts, psum, offsets, cursor, out + 4194304);
  r3_k<<<32, 256, 0, stream>>>(topi, gates, cursor, ptoken, pgate, ppos);
  // 10) expert weights bf16 (plain)
  transpose_k<0><<<dim3(64, 32, 8), tb, 0, stream>>>(
      w1, w1t, nullptr, 1024, 2048, (long)1024 * 2048, (long)1024 * 2048);
  transpose_k<0><<<dim3(32, 64, 8), tb, 0, stream>>>(
      w2, w2t, nullptr, 2048, 1024, (long)2048 * 1024, (long)2048 * 1024);
  // 11) grouped MoE GEMMs
  gemm_k<1024, 2, 2048><<<dim3(16, 64, 8), 256, 0, stream>>>(
      xh, w1t, hbuf, nullptr, offsets, counts, ptoken);
  gemm_k<2048, 3, 1024><<<dim3(8, 64, 8), 256, 0, stream>>>(
      hbuf, w2t, pout, pgate, offsets, counts, nullptr);
  // 12) out = x2 + gathered expert outputs
  final_k<<<4096, 256, 0, stream>>>(x2, pout, ppos, out);
}

// Round 4
// 977.365 us; speedup vs baseline: 1.5220x; 1.5220x over previous
//
#include <hip/hip_runtime.h>

#define T_TOK 4096
#define DM 1024
#define NH 16
#define HDIM 64
#define DFF_ 2048
#define NE 8

typedef __bf16 bf16;
typedef __bf16 bf16x8 __attribute__((ext_vector_type(8)));
typedef __bf16 bf16x4 __attribute__((ext_vector_type(4)));
typedef float f32x4 __attribute__((ext_vector_type(4)));

__device__ __forceinline__ void gload_lds16(const bf16* g, bf16* l) {
  __builtin_amdgcn_global_load_lds(
      (const __attribute__((address_space(1))) void*)g,
      (__attribute__((address_space(3))) void*)l, 16, 0, 0);
}

// ---------------- rmsnorm; MODE 0: single bf16 plane, MODE 1: hi/lo split ----------------
template <int SPLIT>
__global__ __launch_bounds__(256) void rmsnorm_k(
    const float* __restrict__ x, const float* __restrict__ w,
    bf16* __restrict__ outh, bf16* __restrict__ outl) {
  const int t = blockIdx.x, tid = threadIdx.x;
  __shared__ float red[4];
  const f32x4 xv = *(const f32x4*)(x + (size_t)t * DM + tid * 4);
  float ss = xv.x * xv.x + xv.y * xv.y + xv.z * xv.z + xv.w * xv.w;
#pragma unroll
  for (int o = 32; o; o >>= 1) ss += __shfl_xor(ss, o);
  if ((tid & 63) == 0) red[tid >> 6] = ss;
  __syncthreads();
  const float rs = rsqrtf((red[0] + red[1] + red[2] + red[3]) * (1.f / DM) + 1e-6f);
  const f32x4 wv = *(const f32x4*)(w + tid * 4);
  float vv[4] = {xv.x * rs * wv.x, xv.y * rs * wv.y, xv.z * rs * wv.z, xv.w * rs * wv.w};
  bf16x4 h, l;
#pragma unroll
  for (int i = 0; i < 4; i++) {
    h[i] = (bf16)vv[i];
    l[i] = (bf16)(vv[i] - (float)h[i]);
  }
  *(bf16x4*)(outh + (size_t)t * DM + tid * 4) = h;
  if constexpr (SPLIT) *(bf16x4*)(outl + (size_t)t * DM + tid * 4) = l;
}

// ---------------- transpose fp32[R][C] -> bf16[C][R]; optional lo plane ----------------
template <int SPLIT>
__global__ __launch_bounds__(256) void transpose_k(
    const float* __restrict__ src, bf16* __restrict__ dsth, bf16* __restrict__ dstl,
    int R, int C, long sstride, long dstride) {
  src += (long)blockIdx.z * sstride;
  dsth += (long)blockIdx.z * dstride;
  __shared__ float tle[32][33];
  const int tx = threadIdx.x, ty = threadIdx.y;
  const int c0 = blockIdx.x * 32, r0 = blockIdx.y * 32;
#pragma unroll
  for (int j = 0; j < 4; j++)
    tle[ty + 8 * j][tx] = src[(size_t)(r0 + ty + 8 * j) * C + c0 + tx];
  __syncthreads();
#pragma unroll
  for (int j = 0; j < 4; j++) {
    const float v = tle[tx][ty + 8 * j];
    const bf16 h = (bf16)v;
    dsth[(size_t)(c0 + ty + 8 * j) * R + r0 + tx] = h;
    if constexpr (SPLIT) {
      dstl[(size_t)(c0 + ty + 8 * j) * R + r0 + tx] = (bf16)(v - (float)h);
    }
  }
}

// ---------------- split-bf16 fp32-accurate GEMM (Ootomo 3-term), BT stored [N][K] ----------
// MODE 0: rkv out fp32, pad-mask cols>=1024.  MODE 1: out fp32 + residual extraF.
template <int K, int N, int MODE>
__global__ __launch_bounds__(256) void gemm_split_k(
    const bf16* __restrict__ Ah, const bf16* __restrict__ Al,
    const bf16* __restrict__ Bh, const bf16* __restrict__ Bl,
    float* __restrict__ Cout, const float* __restrict__ extraF,
    const int* __restrict__ pad) {
  __shared__ bf16 Ash[128 * 32], Asl[128 * 32], Bsh[128 * 32], Bsl[128 * 32];
  const int tid = threadIdx.x, w = tid >> 6, lane = tid & 63;
  const int n0 = blockIdx.x * 128, m0 = blockIdx.y * 128;
  const int sr0 = (w * 2 + 0) * 16 + (lane >> 2);
  const int sr1 = (w * 2 + 1) * 16 + (lane >> 2);
  const int sc = (lane & 3) * 8;
  const size_t ao0 = (size_t)(m0 + sr0) * K + sc, ao1 = (size_t)(m0 + sr1) * K + sc;
  const size_t bo0 = (size_t)(n0 + sr0) * K + sc, bo1 = (size_t)(n0 + sr1) * K + sc;

  f32x4 acc[4][4] = {};
  const int wm = w >> 1, wn = w & 1;
  const int fm = (wm * 64 + (lane & 15)) * 32 + (lane >> 4) * 8;
  const int fn = (wn * 64 + (lane & 15)) * 32 + (lane >> 4) * 8;
  const int l0 = (w * 2 + 0) * 512, l1 = (w * 2 + 1) * 512;

  for (int kt = 0; kt < K; kt += 32) {
    gload_lds16(Ah + ao0 + kt, Ash + l0);
    gload_lds16(Ah + ao1 + kt, Ash + l1);
    gload_lds16(Al + ao0 + kt, Asl + l0);
    gload_lds16(Al + ao1 + kt, Asl + l1);
    gload_lds16(Bh + bo0 + kt, Bsh + l0);
    gload_lds16(Bh + bo1 + kt, Bsh + l1);
    gload_lds16(Bl + bo0 + kt, Bsl + l0);
    gload_lds16(Bl + bo1 + kt, Bsl + l1);
    __syncthreads();
    bf16x8 afh[4], afl[4], bfh[4], bfl[4];
#pragma unroll
    for (int i = 0; i < 4; i++) {
      afh[i] = *(const bf16x8*)(Ash + fm + i * 512);
      afl[i] = *(const bf16x8*)(Asl + fm + i * 512);
      bfh[i] = *(const bf16x8*)(Bsh + fn + i * 512);
      bfl[i] = *(const bf16x8*)(Bsl + fn + i * 512);
    }
#pragma unroll
    for (int mi = 0; mi < 4; mi++)
#pragma unroll
      for (int ni = 0; ni < 4; ni++) {
        acc[mi][ni] = __builtin_amdgcn_mfma_f32_16x16x32_bf16(afh[mi], bfh[ni], acc[mi][ni], 0, 0, 0);
        acc[mi][ni] = __builtin_amdgcn_mfma_f32_16x16x32_bf16(afh[mi], bfl[ni], acc[mi][ni], 0, 0, 0);
        acc[mi][ni] = __builtin_amdgcn_mfma_f32_16x16x32_bf16(afl[mi], bfh[ni], acc[mi][ni], 0, 0, 0);
      }
    __syncthreads();
  }

  const int qr = (lane >> 4) * 4, cl = lane & 15;
#pragma unroll
  for (int mi = 0; mi < 4; mi++) {
#pragma unroll
    for (int r = 0; r < 4; r++) {
      const int row = m0 + wm * 64 + mi * 16 + qr + r;
      if constexpr (MODE == 0) {
        const float mf = (pad[row] != 0) ? 1.f : 0.f;
#pragma unroll
        for (int ni = 0; ni < 4; ni++) {
          const int col = n0 + wn * 64 + ni * 16 + cl;
          float v = acc[mi][ni][r];
          if (col >= DM) v *= mf;
          Cout[(size_t)row * N + col] = v;
        }
      } else {
#pragma unroll
        for (int ni = 0; ni < 4; ni++) {
          const int col = n0 + wn * 64 + ni * 16 + cl;
          Cout[(size_t)row * N + col] = acc[mi][ni][r] + extraF[(size_t)row * N + col];
        }
      }
    }
  }
}

// ---------------- plain bf16 GEMM for MoE (post-routing, error-tolerant) ----------------
// MODE 2: moe1 (gathered A rows via ptoken, silu, bf16 out). MODE 3: moe2 (*gate, fp32 out).
template <int K, int MODE, int N>
__global__ __launch_bounds__(256) void gemm_k(
    const bf16* __restrict__ A, const bf16* __restrict__ BT, void* __restrict__ Cout,
    const float* __restrict__ extraF, const int* __restrict__ offsets,
    const int* __restrict__ counts, const int* __restrict__ ptoken) {
  __shared__ bf16 As[128 * 32];
  __shared__ bf16 Bs[128 * 32];
  const int tid = threadIdx.x, w = tid >> 6, lane = tid & 63;
  const int n0 = blockIdx.x * 128, m0 = blockIdx.y * 128;
  const int e = blockIdx.z;
  const int cnt = counts[e], offs = offsets[e];
  if (m0 >= cnt) return;
  const int sr0 = (w * 2 + 0) * 16 + (lane >> 2);
  const int sr1 = (w * 2 + 1) * 16 + (lane >> 2);
  const int sc = (lane & 3) * 8;
  const bf16 *a0, *a1;
  if constexpr (MODE == 2) {
    const int g0 = (m0 + sr0 < cnt) ? ptoken[offs + m0 + sr0] : 0;
    const int g1 = (m0 + sr1 < cnt) ? ptoken[offs + m0 + sr1] : 0;
    a0 = A + (size_t)g0 * K + sc;
    a1 = A + (size_t)g1 * K + sc;
  } else {
    const int g0 = offs + ((m0 + sr0 < cnt) ? m0 + sr0 : cnt - 1);
    const int g1 = offs + ((m0 + sr1 < cnt) ? m0 + sr1 : cnt - 1);
    a0 = A + (size_t)g0 * K + sc;
    a1 = A + (size_t)g1 * K + sc;
  }
  const bf16* btb = BT + (size_t)e * N * K;
  const bf16* b0 = btb + (size_t)(n0 + sr0) * K + sc;
  const bf16* b1 = btb + (size_t)(n0 + sr1) * K + sc;

  f32x4 acc[4][4] = {};
  const int wm = w >> 1, wn = w & 1;
  const int fm = (wm * 64 + (lane & 15)) * 32 + (lane >> 4) * 8;
  const int fn = (wn * 64 + (lane & 15)) * 32 + (lane >> 4) * 8;
  const int l0 = (w * 2 + 0) * 512, l1 = (w * 2 + 1) * 512;

  for (int kt = 0; kt < K; kt += 32) {
    gload_lds16(a0 + kt, As + l0);
    gload_lds16(a1 + kt, As + l1);
    gload_lds16(b0 + kt, Bs + l0);
    gload_lds16(b1 + kt, Bs + l1);
    __syncthreads();
    bf16x8 af[4], bfv[4];
#pragma unroll
    for (int i = 0; i < 4; i++) af[i] = *(const bf16x8*)(As + fm + i * 512);
#pragma unroll
    for (int i = 0; i < 4; i++) bfv[i] = *(const bf16x8*)(Bs + fn + i * 512);
#pragma unroll
    for (int mi = 0; mi < 4; mi++)
#pragma unroll
      for (int ni = 0; ni < 4; ni++)
        acc[mi][ni] =
            __builtin_amdgcn_mfma_f32_16x16x32_bf16(af[mi], bfv[ni], acc[mi][ni], 0, 0, 0);
    __syncthreads();
  }

  const int qr = (lane >> 4) * 4, cl = lane & 15;
#pragma unroll
  for (int mi = 0; mi < 4; mi++) {
#pragma unroll
    for (int r = 0; r < 4; r++) {
      const int row = m0 + wm * 64 + mi * 16 + qr + r;
      if (row >= cnt) continue;
      const size_t p = (size_t)(offs + row);
      if constexpr (MODE == 2) {
#pragma unroll
        for (int ni = 0; ni < 4; ni++) {
          const int col = n0 + wn * 64 + ni * 16 + cl;
          const float v = acc[mi][ni][r];
          ((bf16*)Cout)[p * N + col] = (bf16)(v / (1.f + __expf(-v)));  // silu
        }
      } else {
        const float g = extraF[p];
#pragma unroll
        for (int ni = 0; ni < 4; ni++) {
          const int col = n0 + wn * 64 + ni * 16 + cl;
          ((float*)Cout)[p * N + col] = acc[mi][ni][r] * g;
        }
      }
    }
  }
}

// ---------------- bidirectional RWKV scan; fp32 atomic accumulate into y ----------------
__global__ __launch_bounds__(256) void scan_k(
    const float* __restrict__ rkv, const float* __restrict__ decay,
    float* __restrict__ yacc) {
  const int wg = blockIdx.x;
  const int dir = wg & 1, kg = (wg >> 1) & 3, h = (wg >> 3) & 15, b = wg >> 7;
  const int tid = threadIdx.x, w = tid >> 6, lane = tid & 63;
  const int kb = kg * 16 + w * 4;
  __shared__ float ylds[4][16][64];

  const f32x4 dc = *(const f32x4*)(decay + h * HDIM + kb);
  const float wd0 = expf(-expf(dc.x)), wd1 = expf(-expf(dc.y));
  const float wd2 = expf(-expf(dc.z)), wd3 = expf(-expf(dc.w));

  const long base = (long)b * 2048 * 3072;
  const long start = dir ? (long)2047 * 3072 : 0;
  const long stp = dir ? -3072 : 3072;
  const float* rp = rkv + base + start + h * HDIM + kb;
  const float* kp = rp + 1024;
  const float* vp = rkv + base + start + 2048 + h * HDIM + lane;

  float S0 = 0.f, S1 = 0.f, S2 = 0.f, S3 = 0.f;
  f32x4 ka[8], ra[8], kc[8], rc[8];
  float va[8], vc[8], yb[16];
#pragma unroll
  for (int s = 0; s < 8; s++) {
    ka[s] = *(const f32x4*)(kp + (long)s * stp);
    ra[s] = *(const f32x4*)(rp + (long)s * stp);
    va[s] = vp[(long)s * stp];
  }
  for (int c = 0; c < 128; ++c) {
#pragma unroll
    for (int s = 0; s < 8; s++) {
      kc[s] = *(const f32x4*)(kp + (long)(8 + s) * stp);
      rc[s] = *(const f32x4*)(rp + (long)(8 + s) * stp);
      vc[s] = vp[(long)(8 + s) * stp];
    }
#pragma unroll
    for (int s = 0; s < 8; s++) {
      const float vv = va[s];
      const f32x4 Kv = ka[s], Rv = ra[s];
      yb[s] = Rv.x * S0 + Rv.y * S1 + Rv.z * S2 + Rv.w * S3;
      S0 = wd0 * S0 + Kv.x * vv;
      S1 = wd1 * S1 + Kv.y * vv;
      S2 = wd2 * S2 + Kv.z * vv;
      S3 = wd3 * S3 + Kv.w * vv;
    }
    if (c < 127) {
#pragma unroll
      for (int s = 0; s < 8; s++) {
        ka[s] = *(const f32x4*)(kp + (long)(16 + s) * stp);
        ra[s] = *(const f32x4*)(rp + (long)(16 + s) * stp);
        va[s] = vp[(long)(16 + s) * stp];
      }
    }
#pragma unroll
    for (int s = 0; s < 8; s++) {
      const float vv = vc[s];
      const f32x4 Kv = kc[s], Rv = rc[s];
      yb[8 + s] = Rv.x * S0 + Rv.y * S1 + Rv.z * S2 + Rv.w * S3;
      S0 = wd0 * S0 + Kv.x * vv;
      S1 = wd1 * S1 + Kv.y * vv;
      S2 = wd2 * S2 + Kv.z * vv;
      S3 = wd3 * S3 + Kv.w * vv;
    }
    kp += 16 * stp;
    rp += 16 * stp;
    vp += 16 * stp;
#pragma unroll
    for (int s = 0; s < 16; s++) ylds[w][s][lane] = yb[s];
    __syncthreads();
    {
      const int idx = tid * 4, tl = idx >> 6, v0 = idx & 63;
      const f32x4 s0 = *(const f32x4*)&ylds[0][tl][v0];
      const f32x4 s1 = *(const f32x4*)&ylds[1][tl][v0];
      const f32x4 s2 = *(const f32x4*)&ylds[2][tl][v0];
      const f32x4 s3 = *(const f32x4*)&ylds[3][tl][v0];
      const f32x4 sm = s0 + s1 + s2 + s3;
      const int sg = dir ? (2047 - (c * 16 + tl)) : (c * 16 + tl);
      float* yp = yacc + (size_t)(b * 2048 + sg) * DM + h * HDIM + v0;
      atomicAdd(yp + 0, sm.x);
      atomicAdd(yp + 1, sm.y);
      atomicAdd(yp + 2, sm.z);
      atomicAdd(yp + 3, sm.w);
    }
    __syncthreads();
  }
}

// ---------------- y = yacc + 2*c_t*v  ->  hi/lo bf16 planes ----------------
__global__ __launch_bounds__(256) void sum_k(
    const float* __restrict__ rkv, const float* __restrict__ bonus,
    const float* __restrict__ yacc, bf16* __restrict__ yh, bf16* __restrict__ yl) {
  const int tok = blockIdx.x, tid = threadIdx.x;
  const int hv = tid * 4;
  const float* bse = rkv + (size_t)tok * 3072;
  const f32x4 r4 = *(const f32x4*)(bse + hv);
  const f32x4 k4 = *(const f32x4*)(bse + 1024 + hv);
  const f32x4 v4 = *(const f32x4*)(bse + 2048 + hv);
  const f32x4 u4 = *(const f32x4*)(bonus + hv);
  float p = r4.x * u4.x * k4.x + r4.y * u4.y * k4.y + r4.z * u4.z * k4.z + r4.w * u4.w * k4.w;
  p += __shfl_xor(p, 1);
  p += __shfl_xor(p, 2);
  p += __shfl_xor(p, 4);
  p += __shfl_xor(p, 8);  // reduce over the 16 lanes of this head
  const float c2 = 2.f * p;  // bonus appears once per direction
  const f32x4 ya = *(const f32x4*)(yacc + (size_t)tok * DM + hv);
  float yv[4] = {ya.x + c2 * v4.x, ya.y + c2 * v4.y, ya.z + c2 * v4.z, ya.w + c2 * v4.w};
  bf16x4 h, l;
#pragma unroll
  for (int i = 0; i < 4; i++) {
    h[i] = (bf16)yv[i];
    l[i] = (bf16)(yv[i] - (float)h[i]);
  }
  *(bf16x4*)(yh + (size_t)tok * DM + hv) = h;
  *(bf16x4*)(yl + (size_t)tok * DM + hv) = l;
}

// ---------------- router: fp32 logits+softmax+top2; NO atomics ----------------
__global__ __launch_bounds__(256) void router_k(
    const float* __restrict__ x2, const float* __restrict__ nw, const float* __restrict__ rw,
    float* __restrict__ gates, int* __restrict__ topi, float* __restrict__ prbuf) {
  const int t = blockIdx.x, tid = threadIdx.x, lane = tid & 63, wv = tid >> 6;
  __shared__ float red[4];
  __shared__ float lacc[4][8];
  const f32x4 xv = *(const f32x4*)(x2 + (size_t)t * DM + tid * 4);
  float ss = xv.x * xv.x + xv.y * xv.y + xv.z * xv.z + xv.w * xv.w;
#pragma unroll
  for (int o = 32; o; o >>= 1) ss += __shfl_xor(ss, o);
  if (!lane) red[wv] = ss;
  __syncthreads();
  const float rs = rsqrtf((red[0] + red[1] + red[2] + red[3]) * (1.f / DM) + 1e-6f);
  const f32x4 wv4 = *(const f32x4*)(nw + tid * 4);
  float a[8] = {0, 0, 0, 0, 0, 0, 0, 0};
  const float xns[4] = {xv.x * rs * wv4.x, xv.y * rs * wv4.y, xv.z * rs * wv4.z,
                        xv.w * rs * wv4.w};
#pragma unroll
  for (int j = 0; j < 4; j++) {
    const float* rwp = rw + (size_t)(tid * 4 + j) * NE;
    const f32x4 q0 = *(const f32x4*)rwp;
    const f32x4 q1 = *(const f32x4*)(rwp + 4);
    a[0] += xns[j] * q0.x; a[1] += xns[j] * q0.y; a[2] += xns[j] * q0.z; a[3] += xns[j] * q0.w;
    a[4] += xns[j] * q1.x; a[5] += xns[j] * q1.y; a[6] += xns[j] * q1.z; a[7] += xns[j] * q1.w;
  }
#pragma unroll
  for (int e2 = 0; e2 < 8; e2++) {
    float v = a[e2];
#pragma unroll
    for (int o = 32; o; o >>= 1) v += __shfl_xor(v, o);
    a[e2] = v;
  }
  if (!lane) {
#pragma unroll
    for (int e2 = 0; e2 < 8; e2++) lacc[wv][e2] = a[e2];
  }
  __syncthreads();
  if (tid == 0) {
    float l[8];
    for (int e2 = 0; e2 < 8; e2++)
      l[e2] = lacc[0][e2] + lacc[1][e2] + lacc[2][e2] + lacc[3][e2];
    float mx = l[0];
    for (int e2 = 1; e2 < 8; e2++) mx = fmaxf(mx, l[e2]);
    float pr[8], s = 0.f;
    for (int e2 = 0; e2 < 8; e2++) { pr[e2] = expf(l[e2] - mx); s += pr[e2]; }
    const float inv = 1.f / s;
    for (int e2 = 0; e2 < 8; e2++) pr[e2] *= inv;
    int i1 = 0; float v1 = pr[0];
    for (int e2 = 1; e2 < 8; e2++) if (pr[e2] > v1) { v1 = pr[e2]; i1 = e2; }
    int i2 = -1; float v2 = -1.f;
    for (int e2 = 0; e2 < 8; e2++) if (e2 != i1 && pr[e2] > v2) { v2 = pr[e2]; i2 = e2; }
    const float dn = 1.f / (v1 + v2);
    gates[t * 2] = v1 * dn;
    gates[t * 2 + 1] = v2 * dn;
    topi[t * 2] = i1;
    topi[t * 2 + 1] = i2;
    f32x4 p0, p1;
    p0.x = pr[0]; p0.y = pr[1]; p0.z = pr[2]; p0.w = pr[3];
    p1.x = pr[4]; p1.y = pr[5]; p1.z = pr[6]; p1.w = pr[7];
    *(f32x4*)(prbuf + t * 8) = p0;
    *(f32x4*)(prbuf + t * 8 + 4) = p1;
  }
}

// ---------------- single-block routing: hist + prefix scan + partition + aux -------------
// Deterministic, zero global atomics. 8192 slots, 256 threads x 32 slots.
__global__ __launch_bounds__(256) void route_k(
    const int* __restrict__ topi, const float* __restrict__ gates,
    const float* __restrict__ prbuf,
    int* __restrict__ offsets, int* __restrict__ counts,
    int* __restrict__ ptoken, float* __restrict__ pgate, int* __restrict__ ppos,
    float* __restrict__ auxout) {
  const int tid = threadIdx.x;
  __shared__ int hist[256][8];
  __shared__ float pshr[256][8];
  __shared__ int pfx[256][8];
  __shared__ int chunksum[8][8], chunkbase[8][8];
  __shared__ float chunkp[8][8];
  __shared__ int ctot[8], offs_s[8];
  __shared__ float ptot[8];

  int lh[8] = {0, 0, 0, 0, 0, 0, 0, 0};
#pragma unroll 4
  for (int j = 0; j < 32; j++) lh[topi[tid * 32 + j]]++;
  float ps[8] = {0, 0, 0, 0, 0, 0, 0, 0};
  for (int j = 0; j < 16; j++) {
    const int tok = tid * 16 + j;
    const f32x4 q0 = *(const f32x4*)(prbuf + tok * 8);
    const f32x4 q1 = *(const f32x4*)(prbuf + tok * 8 + 4);
    ps[0] += q0.x; ps[1] += q0.y; ps[2] += q0.z; ps[3] += q0.w;
    ps[4] += q1.x; ps[5] += q1.y; ps[6] += q1.z; ps[7] += q1.w;
  }
#pragma unroll
  for (int e = 0; e < 8; e++) { hist[tid][e] = lh[e]; pshr[tid][e] = ps[e]; }
  __syncthreads();
  if (tid < 64) {  // chunk-level partial sums: e = tid>>3 over chunk c = tid&7 (32 threads each)
    const int e = tid >> 3, c = tid & 7;
    int s = 0;
    float p = 0.f;
    for (int t2 = c * 32; t2 < c * 32 + 32; t2++) { s += hist[t2][e]; p += pshr[t2][e]; }
    chunksum[c][e] = s;
    chunkp[c][e] = p;
  }
  __syncthreads();
  if (tid < 8) {
    int run = 0;
    float pr = 0.f;
    for (int c = 0; c < 8; c++) {
      chunkbase[c][tid] = run;
      run += chunksum[c][tid];
      pr += chunkp[c][tid];
    }
    ctot[tid] = run;
    ptot[tid] = pr;
  }
  __syncthreads();
  if (tid == 0) {
    int o = 0;
    float a = 0.f;
    for (int e = 0; e < 8; e++) {
      offs_s[e] = o;
      offsets[e] = o;
      counts[e] = ctot[e];
      a += (float)ctot[e] * ptot[e];
      o += ctot[e];
    }
    auxout[0] = a * (8.f / (8192.f * 4096.f));
  }
  if (tid < 64) {  // per-thread exclusive prefix within chunk
    const int e = tid >> 3, c = tid & 7;
    int run = 0;
    for (int t2 = c * 32; t2 < c * 32 + 32; t2++) {
      pfx[t2][e] = run;
      run += hist[t2][e];
    }
  }
  __syncthreads();
  int rc[8] = {0, 0, 0, 0, 0, 0, 0, 0};
  const int cb = tid >> 5;  // my chunk
#pragma unroll 4
  for (int j = 0; j < 32; j++) {
    const int slot = tid * 32 + j;
    const int e = topi[slot];
    const int pos = offs_s[e] + chunkbase[cb][e] + pfx[tid][e] + rc[e]++;
    ptoken[pos] = slot >> 1;
    pgate[pos] = gates[slot];
    ppos[slot] = pos;
  }
}

// ---------------- final: out = x2 + pair0 + pair1 ----------------
__global__ __launch_bounds__(256) void final_k(
    const float* __restrict__ x2, const float* __restrict__ pout,
    const int* __restrict__ ppos, float* __restrict__ out) {
  const int idx = blockIdx.x * 256 + threadIdx.x;
  const int t = idx >> 8, c = (idx & 255) * 4;
  const int p0 = ppos[t * 2], p1 = ppos[t * 2 + 1];
  const f32x4 a = *(const f32x4*)(x2 + (size_t)t * DM + c);
  const f32x4 b0 = *(const f32x4*)(pout + (size_t)p0 * DM + c);
  const f32x4 b1 = *(const f32x4*)(pout + (size_t)p1 * DM + c);
  const f32x4 o = a + b0 + b1;
  *(f32x4*)(out + (size_t)t * DM + c) = o;
}

extern "C" void kernel_launch(void* const* d_in, const int* in_sizes, int n_in,
                              void* d_out, int out_size, void* d_ws, size_t ws_size,
                              hipStream_t stream) {
  (void)in_sizes; (void)n_in; (void)out_size; (void)ws_size;
  const float* x = (const float*)d_in[0];
  const int* pad = (const int*)d_in[1];
  const float* n1w = (const float*)d_in[2];
  const float* n2w = (const float*)d_in[3];
  const float* Wr = (const float*)d_in[4];
  const float* Wk = (const float*)d_in[5];
  const float* Wv = (const float*)d_in[6];
  const float* Wo = (const float*)d_in[7];
  const float* decay = (const float*)d_in[8];
  const float* bonus = (const float*)d_in[9];
  const float* rw = (const float*)d_in[10];
  const float* w1 = (const float*)d_in[11];
  const float* w2 = (const float*)d_in[12];
  float* out = (float*)d_out;
  char* ws = (char*)d_ws;

  // workspace layout (lifetime-aliased), peak ~180.7 MB
  float* rkv = (float*)(ws + 0);                 // [4096][3072] fp32, 50.3MB
  float* yacc = (float*)(ws + 50331648);         // [4096][1024] fp32, 16.8MB
  float* x2 = (float*)(ws + 67108864);           // 16.8MB
  bf16* xh = (bf16*)(ws + 83886080);             // hi plane 8.4MB (xn1 -> y -> xn2)
  bf16* xl = (bf16*)(ws + 92274688);             // lo plane 8.4MB
  bf16* wbh = (bf16*)(ws + 100663296);           // Wrkv^T hi [3072][1024], 6.3MB
  bf16* wbl = (bf16*)(ws + 106954752);           // Wrkv^T lo, 6.3MB -> ends 113246208
  float* pout = (float*)(ws + 113246208);        // [8192][1024] fp32, 33.6MB -> 146800640
  bf16* hbuf = (bf16*)(ws + 146800640);          // [8192][2048] bf16, 33.6MB -> 180355072
  char* sm = ws + 180355072;                     // tables ~300KB
  int* counts = (int*)(sm);
  int* offsets = (int*)(sm + 64);
  int* topi = (int*)(sm + 128);                  // 8192 ints -> ends 32896
  float* gates = (float*)(sm + 32896);           // 8192 f32  -> ends 65664
  int* ppos = (int*)(sm + 65664);                // 8192 ints -> ends 98432
  int* ptoken = (int*)(sm + 98432);              // 8192 ints -> ends 131200
  float* pgate = (float*)(sm + 131712);          // 8192 f32  -> ends 164480
  float* prbuf = (float*)(sm + 164480);          // [4096][8] f32 -> ends 295552
  // aliased after scan/sum (rkv, yacc dead):
  bf16* w1t = (bf16*)(ws + 0);                   // [8][2048][1024] bf16, 33.6MB
  bf16* w2t = (bf16*)(ws + 33554432);            // [8][1024][2048] bf16, 33.6MB -> 67108864
  // Wo hi/lo aliases Wrkv planes (dead after QKV GEMM):
  bf16* woh = wbh;
  bf16* wol = (bf16*)(ws + 102760448);

  const dim3 tb(32, 8);

  // 1) xn1 = rmsnorm(x) -> hi/lo
  rmsnorm_k<1><<<4096, 256, 0, stream>>>(x, n1w, xh, xl);
  // 2) Wrkv^T hi/lo
  transpose_k<1><<<dim3(32, 32, 1), tb, 0, stream>>>(Wr, wbh, wbl, 1024, 1024, 0, 0);
  transpose_k<1><<<dim3(32, 32, 1), tb, 0, stream>>>(Wk, wbh + 1048576, wbl + 1048576, 1024, 1024, 0, 0);
  transpose_k<1><<<dim3(32, 32, 1), tb, 0, stream>>>(Wv, wbh + 2097152, wbl + 2097152, 1024, 1024, 0, 0);
  // 3) rkv = xn1 @ [Wr|Wk|Wv] (split fp32-accurate), pad-mask k,v planes
  gemm_split_k<1024, 3072, 0><<<dim3(24, 32, 1), 256, 0, stream>>>(
      xh, xl, wbh, wbl, rkv, nullptr, pad);
  // 4) y accumulation (scan, fp32 atomics, disjoint addresses)
  hipMemsetAsync(yacc, 0, 16777216, stream);
  scan_k<<<256, 256, 0, stream>>>(rkv, decay, yacc);
  // 5) Wo^T hi/lo
  transpose_k<1><<<dim3(32, 32, 1), tb, 0, stream>>>(Wo, woh, wol, 1024, 1024, 0, 0);
  // 6) y = yacc + 2*ct*v -> hi/lo planes (reuse xh/xl)
  sum_k<<<4096, 256, 0, stream>>>(rkv, bonus, yacc, xh, xl);
  // 7) x2 = x + y @ Wo (split fp32-accurate)
  gemm_split_k<1024, 1024, 1><<<dim3(8, 32, 1), 256, 0, stream>>>(
      xh, xl, woh, wol, x2, x, nullptr);
  // 8) xn2 = rmsnorm(x2) single bf16 (for MoE)
  rmsnorm_k<0><<<4096, 256, 0, stream>>>(x2, n2w, xh, nullptr);
  // 9) routing: per-token (no atomics) + single-block partition
  router_k<<<4096, 256, 0, stream>>>(x2, n2w, rw, gates, topi, prbuf);
  route_k<<<1, 256, 0, stream>>>(topi, gates, prbuf, offsets, counts, ptoken, pgate,
                                 ppos, out + 4194304);
  // 10) expert weights bf16 (plain)
  transpose_k<0><<<dim3(64, 32, 8), tb, 0, stream>>>(
      w1, w1t, nullptr, 1024, 2048, (long)1024 * 2048, (long)1024 * 2048);
  transpose_k<0><<<dim3(32, 64, 8), tb, 0, stream>>>(
      w2, w2t, nullptr, 2048, 1024, (long)2048 * 1024, (long)2048 * 1024);
  // 11) grouped MoE GEMMs
  gemm_k<1024, 2, 2048><<<dim3(16, 64, 8), 256, 0, stream>>>(
      xh, w1t, hbuf, nullptr, offsets, counts, ptoken);
  gemm_k<2048, 3, 1024><<<dim3(8, 64, 8), 256, 0, stream>>>(
      hbuf, w2t, pout, pgate, offsets, counts, nullptr);
  // 12) out = x2 + gathered expert outputs
  final_k<<<4096, 256, 0, stream>>>(x2, pout, ppos, out);
}

// Round 5
// 847.491 us; speedup vs baseline: 1.7552x; 1.1532x over previous
//
#include <hip/hip_runtime.h>

#define T_TOK 4096
#define DM 1024
#define NH 16
#define HDIM 64
#define DFF_ 2048
#define NE 8

typedef __bf16 bf16;
typedef __bf16 bf16x8 __attribute__((ext_vector_type(8)));
typedef __bf16 bf16x4 __attribute__((ext_vector_type(4)));
typedef float f32x4 __attribute__((ext_vector_type(4)));

__device__ __forceinline__ void gload_lds16(const bf16* g, bf16* l) {
  __builtin_amdgcn_global_load_lds(
      (const __attribute__((address_space(1))) void*)g,
      (__attribute__((address_space(3))) void*)l, 16, 0, 0);
}

// ---------------- rmsnorm; MODE 0: single bf16 plane, MODE 1: hi/lo split ----------------
template <int SPLIT>
__global__ __launch_bounds__(256) void rmsnorm_k(
    const float* __restrict__ x, const float* __restrict__ w,
    bf16* __restrict__ outh, bf16* __restrict__ outl) {
  const int t = blockIdx.x, tid = threadIdx.x;
  __shared__ float red[4];
  const f32x4 xv = *(const f32x4*)(x + (size_t)t * DM + tid * 4);
  float ss = xv.x * xv.x + xv.y * xv.y + xv.z * xv.z + xv.w * xv.w;
#pragma unroll
  for (int o = 32; o; o >>= 1) ss += __shfl_xor(ss, o);
  if ((tid & 63) == 0) red[tid >> 6] = ss;
  __syncthreads();
  const float rs = rsqrtf((red[0] + red[1] + red[2] + red[3]) * (1.f / DM) + 1e-6f);
  const f32x4 wv = *(const f32x4*)(w + tid * 4);
  float vv[4] = {xv.x * rs * wv.x, xv.y * rs * wv.y, xv.z * rs * wv.z, xv.w * rs * wv.w};
  bf16x4 h, l;
#pragma unroll
  for (int i = 0; i < 4; i++) {
    h[i] = (bf16)vv[i];
    l[i] = (bf16)(vv[i] - (float)h[i]);
  }
  *(bf16x4*)(outh + (size_t)t * DM + tid * 4) = h;
  if constexpr (SPLIT) *(bf16x4*)(outl + (size_t)t * DM + tid * 4) = l;
}

// ---------------- transpose fp32[R][C] -> bf16[C][R]; optional lo plane ----------------
template <int SPLIT>
__global__ __launch_bounds__(256) void transpose_k(
    const float* __restrict__ src, bf16* __restrict__ dsth, bf16* __restrict__ dstl,
    int R, int C, long sstride, long dstride) {
  src += (long)blockIdx.z * sstride;
  dsth += (long)blockIdx.z * dstride;
  __shared__ float tle[32][33];
  const int tx = threadIdx.x, ty = threadIdx.y;
  const int c0 = blockIdx.x * 32, r0 = blockIdx.y * 32;
#pragma unroll
  for (int j = 0; j < 4; j++)
    tle[ty + 8 * j][tx] = src[(size_t)(r0 + ty + 8 * j) * C + c0 + tx];
  __syncthreads();
#pragma unroll
  for (int j = 0; j < 4; j++) {
    const float v = tle[tx][ty + 8 * j];
    const bf16 h = (bf16)v;
    dsth[(size_t)(c0 + ty + 8 * j) * R + r0 + tx] = h;
    if constexpr (SPLIT) {
      dstl[(size_t)(c0 + ty + 8 * j) * R + r0 + tx] = (bf16)(v - (float)h);
    }
  }
}

// ---------------- split-bf16 fp32-accurate GEMM (Ootomo 3-term), BT stored [N][K] ----------
// MODE 0: rkv out fp32, pad-mask cols>=1024.  MODE 1: out fp32 + residual extraF.
template <int K, int N, int MODE>
__global__ __launch_bounds__(256) void gemm_split_k(
    const bf16* __restrict__ Ah, const bf16* __restrict__ Al,
    const bf16* __restrict__ Bh, const bf16* __restrict__ Bl,
    float* __restrict__ Cout, const float* __restrict__ extraF,
    const int* __restrict__ pad) {
  __shared__ bf16 Ash[128 * 32], Asl[128 * 32], Bsh[128 * 32], Bsl[128 * 32];
  const int tid = threadIdx.x, w = tid >> 6, lane = tid & 63;
  const int n0 = blockIdx.x * 128, m0 = blockIdx.y * 128;
  const int sr0 = (w * 2 + 0) * 16 + (lane >> 2);
  const int sr1 = (w * 2 + 1) * 16 + (lane >> 2);
  const int sc = (lane & 3) * 8;
  const size_t ao0 = (size_t)(m0 + sr0) * K + sc, ao1 = (size_t)(m0 + sr1) * K + sc;
  const size_t bo0 = (size_t)(n0 + sr0) * K + sc, bo1 = (size_t)(n0 + sr1) * K + sc;

  f32x4 acc[4][4] = {};
  const int wm = w >> 1, wn = w & 1;
  const int fm = (wm * 64 + (lane & 15)) * 32 + (lane >> 4) * 8;
  const int fn = (wn * 64 + (lane & 15)) * 32 + (lane >> 4) * 8;
  const int l0 = (w * 2 + 0) * 512, l1 = (w * 2 + 1) * 512;

  for (int kt = 0; kt < K; kt += 32) {
    gload_lds16(Ah + ao0 + kt, Ash + l0);
    gload_lds16(Ah + ao1 + kt, Ash + l1);
    gload_lds16(Al + ao0 + kt, Asl + l0);
    gload_lds16(Al + ao1 + kt, Asl + l1);
    gload_lds16(Bh + bo0 + kt, Bsh + l0);
    gload_lds16(Bh + bo1 + kt, Bsh + l1);
    gload_lds16(Bl + bo0 + kt, Bsl + l0);
    gload_lds16(Bl + bo1 + kt, Bsl + l1);
    __syncthreads();
    bf16x8 afh[4], afl[4], bfh[4], bfl[4];
#pragma unroll
    for (int i = 0; i < 4; i++) {
      afh[i] = *(const bf16x8*)(Ash + fm + i * 512);
      afl[i] = *(const bf16x8*)(Asl + fm + i * 512);
      bfh[i] = *(const bf16x8*)(Bsh + fn + i * 512);
      bfl[i] = *(const bf16x8*)(Bsl + fn + i * 512);
    }
#pragma unroll
    for (int mi = 0; mi < 4; mi++)
#pragma unroll
      for (int ni = 0; ni < 4; ni++) {
        acc[mi][ni] = __builtin_amdgcn_mfma_f32_16x16x32_bf16(afh[mi], bfh[ni], acc[mi][ni], 0, 0, 0);
        acc[mi][ni] = __builtin_amdgcn_mfma_f32_16x16x32_bf16(afh[mi], bfl[ni], acc[mi][ni], 0, 0, 0);
        acc[mi][ni] = __builtin_amdgcn_mfma_f32_16x16x32_bf16(afl[mi], bfh[ni], acc[mi][ni], 0, 0, 0);
      }
    __syncthreads();
  }

  const int qr = (lane >> 4) * 4, cl = lane & 15;
#pragma unroll
  for (int mi = 0; mi < 4; mi++) {
#pragma unroll
    for (int r = 0; r < 4; r++) {
      const int row = m0 + wm * 64 + mi * 16 + qr + r;
      if constexpr (MODE == 0) {
        const float mf = (pad[row] != 0) ? 1.f : 0.f;
#pragma unroll
        for (int ni = 0; ni < 4; ni++) {
          const int col = n0 + wn * 64 + ni * 16 + cl;
          float v = acc[mi][ni][r];
          if (col >= DM) v *= mf;
          Cout[(size_t)row * N + col] = v;
        }
      } else {
#pragma unroll
        for (int ni = 0; ni < 4; ni++) {
          const int col = n0 + wn * 64 + ni * 16 + cl;
          Cout[(size_t)row * N + col] = acc[mi][ni][r] + extraF[(size_t)row * N + col];
        }
      }
    }
  }
}

// ---------------- plain bf16 GEMM for MoE (post-routing, error-tolerant) ----------------
// MODE 2: moe1 (gathered A rows via ptoken, silu, bf16 out). MODE 3: moe2 (*gate, fp32 out).
template <int K, int MODE, int N>
__global__ __launch_bounds__(256) void gemm_k(
    const bf16* __restrict__ A, const bf16* __restrict__ BT, void* __restrict__ Cout,
    const float* __restrict__ extraF, const int* __restrict__ offsets,
    const int* __restrict__ counts, const int* __restrict__ ptoken) {
  __shared__ bf16 As[128 * 32];
  __shared__ bf16 Bs[128 * 32];
  const int tid = threadIdx.x, w = tid >> 6, lane = tid & 63;
  const int n0 = blockIdx.x * 128, m0 = blockIdx.y * 128;
  const int e = blockIdx.z;
  const int cnt = counts[e], offs = offsets[e];
  if (m0 >= cnt) return;
  const int sr0 = (w * 2 + 0) * 16 + (lane >> 2);
  const int sr1 = (w * 2 + 1) * 16 + (lane >> 2);
  const int sc = (lane & 3) * 8;
  const bf16 *a0, *a1;
  if constexpr (MODE == 2) {
    const int g0 = (m0 + sr0 < cnt) ? ptoken[offs + m0 + sr0] : 0;
    const int g1 = (m0 + sr1 < cnt) ? ptoken[offs + m0 + sr1] : 0;
    a0 = A + (size_t)g0 * K + sc;
    a1 = A + (size_t)g1 * K + sc;
  } else {
    const int g0 = offs + ((m0 + sr0 < cnt) ? m0 + sr0 : cnt - 1);
    const int g1 = offs + ((m0 + sr1 < cnt) ? m0 + sr1 : cnt - 1);
    a0 = A + (size_t)g0 * K + sc;
    a1 = A + (size_t)g1 * K + sc;
  }
  const bf16* btb = BT + (size_t)e * N * K;
  const bf16* b0 = btb + (size_t)(n0 + sr0) * K + sc;
  const bf16* b1 = btb + (size_t)(n0 + sr1) * K + sc;

  f32x4 acc[4][4] = {};
  const int wm = w >> 1, wn = w & 1;
  const int fm = (wm * 64 + (lane & 15)) * 32 + (lane >> 4) * 8;
  const int fn = (wn * 64 + (lane & 15)) * 32 + (lane >> 4) * 8;
  const int l0 = (w * 2 + 0) * 512, l1 = (w * 2 + 1) * 512;

  for (int kt = 0; kt < K; kt += 32) {
    gload_lds16(a0 + kt, As + l0);
    gload_lds16(a1 + kt, As + l1);
    gload_lds16(b0 + kt, Bs + l0);
    gload_lds16(b1 + kt, Bs + l1);
    __syncthreads();
    bf16x8 af[4], bfv[4];
#pragma unroll
    for (int i = 0; i < 4; i++) af[i] = *(const bf16x8*)(As + fm + i * 512);
#pragma unroll
    for (int i = 0; i < 4; i++) bfv[i] = *(const bf16x8*)(Bs + fn + i * 512);
#pragma unroll
    for (int mi = 0; mi < 4; mi++)
#pragma unroll
      for (int ni = 0; ni < 4; ni++)
        acc[mi][ni] =
            __builtin_amdgcn_mfma_f32_16x16x32_bf16(af[mi], bfv[ni], acc[mi][ni], 0, 0, 0);
    __syncthreads();
  }

  const int qr = (lane >> 4) * 4, cl = lane & 15;
#pragma unroll
  for (int mi = 0; mi < 4; mi++) {
#pragma unroll
    for (int r = 0; r < 4; r++) {
      const int row = m0 + wm * 64 + mi * 16 + qr + r;
      if (row >= cnt) continue;
      const size_t p = (size_t)(offs + row);
      if constexpr (MODE == 2) {
#pragma unroll
        for (int ni = 0; ni < 4; ni++) {
          const int col = n0 + wn * 64 + ni * 16 + cl;
          const float v = acc[mi][ni][r];
          ((bf16*)Cout)[p * N + col] = (bf16)(v / (1.f + __expf(-v)));  // silu
        }
      } else {
        const float g = extraF[p];
#pragma unroll
        for (int ni = 0; ni < 4; ni++) {
          const int col = n0 + wn * 64 + ni * 16 + cl;
          ((float*)Cout)[p * N + col] = acc[mi][ni][r] * g;
        }
      }
    }
  }
}

// ---------------- bidirectional RWKV scan -> 4 fp32 partial streams (no atomics) --------
// WG = (b,h,dir,kg2-half of k). 4 waves x 8 k/lane; lane = v. LDS-reduce waves,
// streaming f32x4 stores into ypf[dir*2+kg2][token][1024].
__global__ __launch_bounds__(256, 1) void scan_k(
    const float* __restrict__ rkv, const float* __restrict__ decay,
    float* __restrict__ ypf) {
  const int wg = blockIdx.x;
  const int dir = wg & 1, kg2 = (wg >> 1) & 1, h = (wg >> 2) & 15, b = wg >> 6;
  const int tid = threadIdx.x, w = tid >> 6, lane = tid & 63;
  const int kb = kg2 * 32 + w * 8;
  __shared__ float ylds[4][16][64];

  float wd[8];
#pragma unroll
  for (int i = 0; i < 8; i++) wd[i] = expf(-expf(decay[h * HDIM + kb + i]));

  const long base = (long)b * 2048 * 3072;
  const long start = dir ? (long)2047 * 3072 : 0;
  const long stp = dir ? -3072 : 3072;
  const float* rp = rkv + base + start + h * HDIM + kb;
  const float* kp = rp + 1024;
  const float* vp = rkv + base + start + 2048 + h * HDIM + lane;

  float S[8];
#pragma unroll
  for (int i = 0; i < 8; i++) S[i] = 0.f;

  // double-buffered 8-token halves
  float rA[8][8], kA[8][8], vA[8], rB[8][8], kB[8][8], vB[8];

#define LOADH(RB, KB, VB, NT)                                              \
  _Pragma("unroll") for (int s = 0; s < 8; s++) {                          \
    *(f32x4*)&RB[s][0] = *(const f32x4*)(rp + (long)((NT) + s) * stp);     \
    *(f32x4*)&RB[s][4] = *(const f32x4*)(rp + (long)((NT) + s) * stp + 4); \
    *(f32x4*)&KB[s][0] = *(const f32x4*)(kp + (long)((NT) + s) * stp);     \
    *(f32x4*)&KB[s][4] = *(const f32x4*)(kp + (long)((NT) + s) * stp + 4); \
    VB[s] = vp[(long)((NT) + s) * stp];                                    \
  }
#define COMPH(RB, KB, VB, QOFF)                                            \
  _Pragma("unroll") for (int s = 0; s < 8; s++) {                          \
    const float vv = VB[s];                                                \
    float y = 0.f;                                                         \
    _Pragma("unroll") for (int i = 0; i < 8; i++) {                        \
      y += RB[s][i] * S[i];                                                \
      S[i] = wd[i] * S[i] + KB[s][i] * vv;                                 \
    }                                                                      \
    ylds[w][(QOFF) + s][lane] = y;                                         \
  }

  LOADH(rA, kA, vA, 0);
  for (int c = 0; c < 128; ++c) {
    LOADH(rB, kB, vB, 8);
    COMPH(rA, kA, vA, 0);
    if (c < 127) { LOADH(rA, kA, vA, 16); }
    COMPH(rB, kB, vB, 8);
    rp += 16 * stp;
    kp += 16 * stp;
    vp += 16 * stp;
    __syncthreads();
    {
      const int idx = tid * 4, tl = idx >> 6, v0 = idx & 63;
      const f32x4 s0 = *(const f32x4*)&ylds[0][tl][v0];
      const f32x4 s1 = *(const f32x4*)&ylds[1][tl][v0];
      const f32x4 s2 = *(const f32x4*)&ylds[2][tl][v0];
      const f32x4 s3 = *(const f32x4*)&ylds[3][tl][v0];
      const f32x4 sm = s0 + s1 + s2 + s3;
      const int sg = dir ? (2047 - (c * 16 + tl)) : (c * 16 + tl);
      *(f32x4*)(ypf + ((size_t)(dir * 2 + kg2) * T_TOK + (b * 2048 + sg)) * DM +
                h * HDIM + v0) = sm;
    }
    __syncthreads();
  }
#undef LOADH
#undef COMPH
}

// ---------------- y = sum(4 streams) + 2*c_t*v  ->  hi/lo bf16 planes ----------------
__global__ __launch_bounds__(256) void sum_k(
    const float* __restrict__ rkv, const float* __restrict__ bonus,
    const float* __restrict__ ypf, bf16* __restrict__ yh, bf16* __restrict__ yl) {
  const int tok = blockIdx.x, tid = threadIdx.x;
  const int hv = tid * 4;
  const float* bse = rkv + (size_t)tok * 3072;
  const f32x4 r4 = *(const f32x4*)(bse + hv);
  const f32x4 k4 = *(const f32x4*)(bse + 1024 + hv);
  const f32x4 v4 = *(const f32x4*)(bse + 2048 + hv);
  const f32x4 u4 = *(const f32x4*)(bonus + hv);
  float p = r4.x * u4.x * k4.x + r4.y * u4.y * k4.y + r4.z * u4.z * k4.z + r4.w * u4.w * k4.w;
  p += __shfl_xor(p, 1);
  p += __shfl_xor(p, 2);
  p += __shfl_xor(p, 4);
  p += __shfl_xor(p, 8);  // reduce over the 16 lanes of this head
  const float c2 = 2.f * p;  // bonus appears once per direction
  f32x4 acc;
  acc.x = c2 * v4.x; acc.y = c2 * v4.y; acc.z = c2 * v4.z; acc.w = c2 * v4.w;
#pragma unroll
  for (int st = 0; st < 4; ++st) {
    const f32x4 yv = *(const f32x4*)(ypf + ((size_t)st * T_TOK + tok) * DM + hv);
    acc.x += yv.x; acc.y += yv.y; acc.z += yv.z; acc.w += yv.w;
  }
  float yv4[4] = {acc.x, acc.y, acc.z, acc.w};
  bf16x4 h, l;
#pragma unroll
  for (int i = 0; i < 4; i++) {
    h[i] = (bf16)yv4[i];
    l[i] = (bf16)(yv4[i] - (float)h[i]);
  }
  *(bf16x4*)(yh + (size_t)tok * DM + hv) = h;
  *(bf16x4*)(yl + (size_t)tok * DM + hv) = l;
}

// ---------------- router: fp32 logits+softmax+top2; NO atomics ----------------
__global__ __launch_bounds__(256) void router_k(
    const float* __restrict__ x2, const float* __restrict__ nw, const float* __restrict__ rw,
    float* __restrict__ gates, int* __restrict__ topi, float* __restrict__ prbuf) {
  const int t = blockIdx.x, tid = threadIdx.x, lane = tid & 63, wv = tid >> 6;
  __shared__ float red[4];
  __shared__ float lacc[4][8];
  const f32x4 xv = *(const f32x4*)(x2 + (size_t)t * DM + tid * 4);
  float ss = xv.x * xv.x + xv.y * xv.y + xv.z * xv.z + xv.w * xv.w;
#pragma unroll
  for (int o = 32; o; o >>= 1) ss += __shfl_xor(ss, o);
  if (!lane) red[wv] = ss;
  __syncthreads();
  const float rs = rsqrtf((red[0] + red[1] + red[2] + red[3]) * (1.f / DM) + 1e-6f);
  const f32x4 wv4 = *(const f32x4*)(nw + tid * 4);
  float a[8] = {0, 0, 0, 0, 0, 0, 0, 0};
  const float xns[4] = {xv.x * rs * wv4.x, xv.y * rs * wv4.y, xv.z * rs * wv4.z,
                        xv.w * rs * wv4.w};
#pragma unroll
  for (int j = 0; j < 4; j++) {
    const float* rwp = rw + (size_t)(tid * 4 + j) * NE;
    const f32x4 q0 = *(const f32x4*)rwp;
    const f32x4 q1 = *(const f32x4*)(rwp + 4);
    a[0] += xns[j] * q0.x; a[1] += xns[j] * q0.y; a[2] += xns[j] * q0.z; a[3] += xns[j] * q0.w;
    a[4] += xns[j] * q1.x; a[5] += xns[j] * q1.y; a[6] += xns[j] * q1.z; a[7] += xns[j] * q1.w;
  }
#pragma unroll
  for (int e2 = 0; e2 < 8; e2++) {
    float v = a[e2];
#pragma unroll
    for (int o = 32; o; o >>= 1) v += __shfl_xor(v, o);
    a[e2] = v;
  }
  if (!lane) {
#pragma unroll
    for (int e2 = 0; e2 < 8; e2++) lacc[wv][e2] = a[e2];
  }
  __syncthreads();
  if (tid == 0) {
    float l[8];
    for (int e2 = 0; e2 < 8; e2++)
      l[e2] = lacc[0][e2] + lacc[1][e2] + lacc[2][e2] + lacc[3][e2];
    float mx = l[0];
    for (int e2 = 1; e2 < 8; e2++) mx = fmaxf(mx, l[e2]);
    float pr[8], s = 0.f;
    for (int e2 = 0; e2 < 8; e2++) { pr[e2] = expf(l[e2] - mx); s += pr[e2]; }
    const float inv = 1.f / s;
    for (int e2 = 0; e2 < 8; e2++) pr[e2] *= inv;
    int i1 = 0; float v1 = pr[0];
    for (int e2 = 1; e2 < 8; e2++) if (pr[e2] > v1) { v1 = pr[e2]; i1 = e2; }
    int i2 = -1; float v2 = -1.f;
    for (int e2 = 0; e2 < 8; e2++) if (e2 != i1 && pr[e2] > v2) { v2 = pr[e2]; i2 = e2; }
    const float dn = 1.f / (v1 + v2);
    gates[t * 2] = v1 * dn;
    gates[t * 2 + 1] = v2 * dn;
    topi[t * 2] = i1;
    topi[t * 2 + 1] = i2;
    f32x4 p0, p1;
    p0.x = pr[0]; p0.y = pr[1]; p0.z = pr[2]; p0.w = pr[3];
    p1.x = pr[4]; p1.y = pr[5]; p1.z = pr[6]; p1.w = pr[7];
    *(f32x4*)(prbuf + t * 8) = p0;
    *(f32x4*)(prbuf + t * 8 + 4) = p1;
  }
}

// ---------------- single-block routing: hist + prefix scan + partition + aux -------------
__global__ __launch_bounds__(256) void route_k(
    const int* __restrict__ topi, const float* __restrict__ gates,
    const float* __restrict__ prbuf,
    int* __restrict__ offsets, int* __restrict__ counts,
    int* __restrict__ ptoken, float* __restrict__ pgate, int* __restrict__ ppos,
    float* __restrict__ auxout) {
  const int tid = threadIdx.x;
  __shared__ int hist[256][8];
  __shared__ float pshr[256][8];
  __shared__ int pfx[256][8];
  __shared__ int chunksum[8][8], chunkbase[8][8];
  __shared__ float chunkp[8][8];
  __shared__ int ctot[8], offs_s[8];
  __shared__ float ptot[8];

  int lh[8] = {0, 0, 0, 0, 0, 0, 0, 0};
#pragma unroll 4
  for (int j = 0; j < 32; j++) lh[topi[tid * 32 + j]]++;
  float ps[8] = {0, 0, 0, 0, 0, 0, 0, 0};
  for (int j = 0; j < 16; j++) {
    const int tok = tid * 16 + j;
    const f32x4 q0 = *(const f32x4*)(prbuf + tok * 8);
    const f32x4 q1 = *(const f32x4*)(prbuf + tok * 8 + 4);
    ps[0] += q0.x; ps[1] += q0.y; ps[2] += q0.z; ps[3] += q0.w;
    ps[4] += q1.x; ps[5] += q1.y; ps[6] += q1.z; ps[7] += q1.w;
  }
#pragma unroll
  for (int e = 0; e < 8; e++) { hist[tid][e] = lh[e]; pshr[tid][e] = ps[e]; }
  __syncthreads();
  if (tid < 64) {
    const int e = tid >> 3, c = tid & 7;
    int s = 0;
    float p = 0.f;
    for (int t2 = c * 32; t2 < c * 32 + 32; t2++) { s += hist[t2][e]; p += pshr[t2][e]; }
    chunksum[c][e] = s;
    chunkp[c][e] = p;
  }
  __syncthreads();
  if (tid < 8) {
    int run = 0;
    float pr = 0.f;
    for (int c = 0; c < 8; c++) {
      chunkbase[c][tid] = run;
      run += chunksum[c][tid];
      pr += chunkp[c][tid];
    }
    ctot[tid] = run;
    ptot[tid] = pr;
  }
  __syncthreads();
  if (tid == 0) {
    int o = 0;
    float a = 0.f;
    for (int e = 0; e < 8; e++) {
      offs_s[e] = o;
      offsets[e] = o;
      counts[e] = ctot[e];
      a += (float)ctot[e] * ptot[e];
      o += ctot[e];
    }
    auxout[0] = a * (8.f / (8192.f * 4096.f));
  }
  if (tid < 64) {
    const int e = tid >> 3, c = tid & 7;
    int run = 0;
    for (int t2 = c * 32; t2 < c * 32 + 32; t2++) {
      pfx[t2][e] = run;
      run += hist[t2][e];
    }
  }
  __syncthreads();
  int rc[8] = {0, 0, 0, 0, 0, 0, 0, 0};
  const int cb = tid >> 5;
#pragma unroll 4
  for (int j = 0; j < 32; j++) {
    const int slot = tid * 32 + j;
    const int e = topi[slot];
    const int pos = offs_s[e] + chunkbase[cb][e] + pfx[tid][e] + rc[e]++;
    ptoken[pos] = slot >> 1;
    pgate[pos] = gates[slot];
    ppos[slot] = pos;
  }
}

// ---------------- final: out = x2 + pair0 + pair1 ----------------
__global__ __launch_bounds__(256) void final_k(
    const float* __restrict__ x2, const float* __restrict__ pout,
    const int* __restrict__ ppos, float* __restrict__ out) {
  const int idx = blockIdx.x * 256 + threadIdx.x;
  const int t = idx >> 8, c = (idx & 255) * 4;
  const int p0 = ppos[t * 2], p1 = ppos[t * 2 + 1];
  const f32x4 a = *(const f32x4*)(x2 + (size_t)t * DM + c);
  const f32x4 b0 = *(const f32x4*)(pout + (size_t)p0 * DM + c);
  const f32x4 b1 = *(const f32x4*)(pout + (size_t)p1 * DM + c);
  const f32x4 o = a + b0 + b1;
  *(f32x4*)(out + (size_t)t * DM + c) = o;
}

extern "C" void kernel_launch(void* const* d_in, const int* in_sizes, int n_in,
                              void* d_out, int out_size, void* d_ws, size_t ws_size,
                              hipStream_t stream) {
  (void)in_sizes; (void)n_in; (void)out_size; (void)ws_size;
  const float* x = (const float*)d_in[0];
  const int* pad = (const int*)d_in[1];
  const float* n1w = (const float*)d_in[2];
  const float* n2w = (const float*)d_in[3];
  const float* Wr = (const float*)d_in[4];
  const float* Wk = (const float*)d_in[5];
  const float* Wv = (const float*)d_in[6];
  const float* Wo = (const float*)d_in[7];
  const float* decay = (const float*)d_in[8];
  const float* bonus = (const float*)d_in[9];
  const float* rw = (const float*)d_in[10];
  const float* w1 = (const float*)d_in[11];
  const float* w2 = (const float*)d_in[12];
  float* out = (float*)d_out;
  char* ws = (char*)d_ws;

  // workspace layout (lifetime-aliased), peak ~180.7 MB
  float* rkv = (float*)(ws + 0);                 // [4096][3072] fp32, 50.3MB
  float* x2 = (float*)(ws + 67108864);           // 16.8MB
  bf16* xh = (bf16*)(ws + 83886080);             // hi plane 8.4MB (xn1 -> y -> xn2)
  bf16* xl = (bf16*)(ws + 92274688);             // lo plane 8.4MB
  bf16* wbh = (bf16*)(ws + 100663296);           // Wrkv^T hi [3072][1024], 6.3MB
  bf16* wbl = (bf16*)(ws + 106954752);           // Wrkv^T lo, 6.3MB -> ends 113246208
  float* ypf = (float*)(ws + 113246208);         // [4][4096][1024] fp32 streams, 67MB (scan window)
  float* pout = (float*)(ws + 113246208);        // aliases ypf (dead after sum_k)
  bf16* hbuf = (bf16*)(ws + 146800640);          // [8192][2048] bf16, 33.6MB -> 180355072
  char* sm = ws + 180355072;                     // tables ~300KB
  int* counts = (int*)(sm);
  int* offsets = (int*)(sm + 64);
  int* topi = (int*)(sm + 128);
  float* gates = (float*)(sm + 32896);
  int* ppos = (int*)(sm + 65664);
  int* ptoken = (int*)(sm + 98432);
  float* pgate = (float*)(sm + 131712);
  float* prbuf = (float*)(sm + 164480);
  // aliased after scan/sum (rkv dead):
  bf16* w1t = (bf16*)(ws + 0);                   // [8][2048][1024] bf16, 33.6MB
  bf16* w2t = (bf16*)(ws + 33554432);            // [8][1024][2048] bf16, 33.6MB -> 67108864
  bf16* woh = wbh;
  bf16* wol = (bf16*)(ws + 102760448);

  const dim3 tb(32, 8);

  // 1) xn1 = rmsnorm(x) -> hi/lo
  rmsnorm_k<1><<<4096, 256, 0, stream>>>(x, n1w, xh, xl);
  // 2) Wrkv^T hi/lo
  transpose_k<1><<<dim3(32, 32, 1), tb, 0, stream>>>(Wr, wbh, wbl, 1024, 1024, 0, 0);
  transpose_k<1><<<dim3(32, 32, 1), tb, 0, stream>>>(Wk, wbh + 1048576, wbl + 1048576, 1024, 1024, 0, 0);
  transpose_k<1><<<dim3(32, 32, 1), tb, 0, stream>>>(Wv, wbh + 2097152, wbl + 2097152, 1024, 1024, 0, 0);
  // 3) rkv = xn1 @ [Wr|Wk|Wv] (split fp32-accurate), pad-mask k,v planes
  gemm_split_k<1024, 3072, 0><<<dim3(24, 32, 1), 256, 0, stream>>>(
      xh, xl, wbh, wbl, rkv, nullptr, pad);
  // 4) bidirectional scan -> 4 fp32 partial streams (streaming stores, no atomics)
  scan_k<<<128, 256, 0, stream>>>(rkv, decay, ypf);
  // 5) Wo^T hi/lo
  transpose_k<1><<<dim3(32, 32, 1), tb, 0, stream>>>(Wo, woh, wol, 1024, 1024, 0, 0);
  // 6) y = sum(streams) + 2*ct*v -> hi/lo planes (reuse xh/xl)
  sum_k<<<4096, 256, 0, stream>>>(rkv, bonus, ypf, xh, xl);
  // 7) x2 = x + y @ Wo (split fp32-accurate)
  gemm_split_k<1024, 1024, 1><<<dim3(8, 32, 1), 256, 0, stream>>>(
      xh, xl, woh, wol, x2, x, nullptr);
  // 8) xn2 = rmsnorm(x2) single bf16 (for MoE)
  rmsnorm_k<0><<<4096, 256, 0, stream>>>(x2, n2w, xh, nullptr);
  // 9) routing: per-token (no atomics) + single-block partition
  router_k<<<4096, 256, 0, stream>>>(x2, n2w, rw, gates, topi, prbuf);
  route_k<<<1, 256, 0, stream>>>(topi, gates, prbuf, offsets, counts, ptoken, pgate,
                                 ppos, out + 4194304);
  // 10) expert weights bf16 (plain)
  transpose_k<0><<<dim3(64, 32, 8), tb, 0, stream>>>(
      w1, w1t, nullptr, 1024, 2048, (long)1024 * 2048, (long)1024 * 2048);
  transpose_k<0><<<dim3(32, 64, 8), tb, 0, stream>>>(
      w2, w2t, nullptr, 2048, 1024, (long)2048 * 1024, (long)2048 * 1024);
  // 11) grouped MoE GEMMs
  gemm_k<1024, 2, 2048><<<dim3(16, 64, 8), 256, 0, stream>>>(
      xh, w1t, hbuf, nullptr, offsets, counts, ptoken);
  gemm_k<2048, 3, 1024><<<dim3(8, 64, 8), 256, 0, stream>>>(
      hbuf, w2t, pout, pgate, offsets, counts, nullptr);
  // 12) out = x2 + gathered expert outputs
  final_k<<<4096, 256, 0, stream>>>(x2, pout, ppos, out);
}